// Round 11
// baseline (1370.833 us; speedup 1.0000x reference)
//
#include <hip/hip_runtime.h>
#include <hip/hip_fp16.h>
#include <math.h>

#define N 2048
#define D 256
#define NM (N*N)
#define REG 0.1f
#define EPSF 1e-10f
#define INV_N (1.0f/2048.0f)
#define P0CONST (1.0f/(2048.0f*2048.0f))
#define PROX 5
#define SINK 100
#define KSCALE 256.0f       // cancels exactly in Sinkhorn (u, P invariant)
#define TOL 4e-6f
#define SMEM_BYTES (131072 + 256)
#define SYS 64              // sync slot stride in ints (256B -> no false sharing)
#define SLOTS_PER_MAT 26    // leaves[2][8], root[2], release[8]

__device__ __forceinline__ float waveReduceSum(float v){
#pragma unroll
    for(int o=32;o;o>>=1) v += __shfl_xor(v,o,64);
    return v;
}
__device__ __forceinline__ float waveReduceMax(float v){
#pragma unroll
    for(int o=32;o;o>>=1) v = fmaxf(v, __shfl_xor(v,o,64));
    return v;
}

// lane-contiguous LDS swizzle: column c (0..2047) -> half-index within row.
// lane l owns columns [l*32, l*32+32).
__device__ __forceinline__ int swz(int c){
    return ((c>>3)&3)*512 + ((c>>5)<<3) + (c&7);
}

// ---------------- row squared-norms of x and y ----------------
__global__ __launch_bounds__(256) void norms_k(const float* __restrict__ x,
                                               const float* __restrict__ y,
                                               float* __restrict__ nx,
                                               float* __restrict__ ny){
    const float* src = blockIdx.y ? y : x;
    float* dst       = blockIdx.y ? ny : nx;
    int w = threadIdx.x >> 6, lane = threadIdx.x & 63;
    int row = blockIdx.x*4 + w;
    const float4* r4 = (const float4*)(src + (size_t)row*D);
    float4 f = r4[lane];
    float s = f.x*f.x + f.y*f.y + f.z*f.z + f.w*f.w;
    s = waveReduceSum(s);
    if(lane==0) dst[row] = s;
}

// ---------------- C = |a_i|^2 + |b_j|^2 - 2 a_i.b_j  (3 matrices) --------
// accumulation order identical for (i,j)/(j,i) -> C_xx, C_yy bitwise symmetric.
__global__ __launch_bounds__(256) void sqdist_k(const float* __restrict__ x,
                                                const float* __restrict__ y,
                                                const float* __restrict__ nx,
                                                const float* __restrict__ ny,
                                                float* __restrict__ Cb){
    int mat = blockIdx.y;
    const float* A  = (mat<2)  ? x  : y;
    const float* B  = (mat==0) ? x  : y;
    const float* na = (mat<2)  ? nx : ny;
    const float* nb = (mat==0) ? nx : ny;
    float* Cm = Cb + (size_t)mat*NM;
    int bm = blockIdx.x >> 5, bn = blockIdx.x & 31;
    __shared__ float As[32][68];
    __shared__ float Bs[32][68];
    int tid = threadIdx.x;
    int tr = tid >> 4, tc = tid & 15;
    float acc[4][4] = {};
    for(int kb=0; kb<8; ++kb){
#pragma unroll
        for(int i=0;i<2;++i){
            int id = tid + 256*i;
            int r = id >> 3, c4 = id & 7;
            float4 a = *(const float4*)(A + (size_t)(bm*64 + r)*D + kb*32 + c4*4);
            As[c4*4+0][r]=a.x; As[c4*4+1][r]=a.y; As[c4*4+2][r]=a.z; As[c4*4+3][r]=a.w;
            float4 b = *(const float4*)(B + (size_t)(bn*64 + r)*D + kb*32 + c4*4);
            Bs[c4*4+0][r]=b.x; Bs[c4*4+1][r]=b.y; Bs[c4*4+2][r]=b.z; Bs[c4*4+3][r]=b.w;
        }
        __syncthreads();
#pragma unroll
        for(int d=0; d<32; ++d){
            float4 a = *(const float4*)&As[d][4*tr];
            float4 b = *(const float4*)&Bs[d][4*tc];
            acc[0][0] += a.x*b.x; acc[0][1] += a.x*b.y; acc[0][2] += a.x*b.z; acc[0][3] += a.x*b.w;
            acc[1][0] += a.y*b.x; acc[1][1] += a.y*b.y; acc[1][2] += a.y*b.z; acc[1][3] += a.y*b.w;
            acc[2][0] += a.z*b.x; acc[2][1] += a.z*b.y; acc[2][2] += a.z*b.z; acc[2][3] += a.z*b.w;
            acc[3][0] += a.w*b.x; acc[3][1] += a.w*b.y; acc[3][2] += a.w*b.z; acc[3][3] += a.w*b.w;
        }
        __syncthreads();
    }
    float nb0 = nb[bn*64 + tc*4 + 0];
    float nb1 = nb[bn*64 + tc*4 + 1];
    float nb2 = nb[bn*64 + tc*4 + 2];
    float nb3 = nb[bn*64 + tc*4 + 3];
#pragma unroll
    for(int i=0;i<4;++i){
        int row = bm*64 + tr*4 + i;
        float nr = na[row];
        float4 o;
        o.x = nr + nb0 - 2.0f*acc[i][0];
        o.y = nr + nb1 - 2.0f*acc[i][1];
        o.z = nr + nb2 - 2.0f*acc[i][2];
        o.w = nr + nb3 - 2.0f*acc[i][3];
        *(float4*)(Cm + (size_t)row*N + bn*64 + tc*4) = o;
    }
}

// ================= persistent cooperative kernel: full 3-chain prox-Sinkhorn =============
// 256 blocks x 1024 threads. Blocks 0-63: xx, 64-127: yy, 128-255: xy.
// Tree barrier: 8 leaf arrival words -> root -> 8 release words (per matrix, 2 parities).
__global__ __launch_bounds__(1024) void coop_k(const float* __restrict__ C,
                                               float* __restrict__ Pa,
                                               float* __restrict__ Pb,
                                               float* __restrict__ ug,
                                               float* __restrict__ vg,
                                               float* __restrict__ maxsl,
                                               int* __restrict__ sync_){
    extern __shared__ char smem[];
    __half* Kl   = (__half*)smem;              // 32 rows (sym) or 16 K rows (xy)
    __half* KTl  = (__half*)(smem + 65536);    // xy: 16 KT rows
    float*  sRed = (float*)(smem + 131072);
    int*    sVote= (int*)(smem + 131072 + 64); // [0]=block vote box, [1]=latch flag

    const int tid = threadIdx.x;
    const int w = tid >> 6, lane = tid & 63;
    int bid = blockIdx.x;
    int m, nblk, row0, nrows, leafId, leafN;
    if(bid < 64)      { m=0; nblk=64;  nrows=32; row0=bid*32;       leafId=bid&7;       leafN=8;  }
    else if(bid <128) { m=2; nblk=64;  nrows=32; row0=(bid-64)*32;  leafId=(bid-64)&7;  leafN=8;  }
    else              { m=1; nblk=128; nrows=16; row0=(bid-128)*16; leafId=(bid-128)&7; leafN=16; }
    int* SYB = sync_ + m*SLOTS_PER_MAT*SYS;
    // slots: [par*8+leaf]=leaf arrivals(lo16)+votes(hi16); [16+par]=root; [18+leaf]=release gen<<1|flag
    const float* Cm = C + (size_t)m*NM;
    float* um = ug + m*N;
    float* vm = vg + m*N;
    const float lp0 = __logf(P0CONST + EPSF);
    int bcount = 0;

    // tree barrier with fused all-vote; returns latch flag
    auto MATBARV = [&](int wantVote)->int{
        __syncthreads();
        if(tid==0){
            unsigned mv = wantVote ? (unsigned)sVote[0] : 0u;
            int par = bcount & 1;
            unsigned* leaf = (unsigned*)(SYB + (size_t)(par*8 + leafId)*SYS);
            unsigned* root = (unsigned*)(SYB + (size_t)(16 + par)*SYS);
            unsigned* rel  = (unsigned*)(SYB + (size_t)(18 + leafId)*SYS);
            __threadfence();                       // flush u/v shard before arrival
            unsigned old = atomicAdd(leaf, 1u | (mv<<16));
            if((old & 0xFFFFu) == (unsigned)(leafN-1)){
                unsigned lv = (old>>16) + mv;
                unsigned rold = atomicAdd(root, 1u | (lv<<16));
                if((rold & 0xFFFFu) == 7u){
                    unsigned tv = (rold>>16) + lv;
                    unsigned relv = ((unsigned)(bcount+1)<<1) | (unsigned)(tv == (unsigned)nblk);
                    for(int i=0;i<8;++i)
                        atomicExch((unsigned*)(SYB + (size_t)(18+i)*SYS), relv);
                    // resets off the critical path (slot reuse gated by barrier k+1)
                    for(int i=0;i<8;++i)
                        atomicExch((unsigned*)(SYB + (size_t)(par*8+i)*SYS), 0u);
                    atomicExch(root, 0u);
                }
            }
            unsigned g;
            for(;;){
                g = __hip_atomic_load(rel, __ATOMIC_RELAXED, __HIP_MEMORY_SCOPE_AGENT);
                if((int)(g>>1) >= bcount+1) break;
                __builtin_amdgcn_s_sleep(1);
            }
            __threadfence();                       // invalidate stale u/v before reads
            sVote[1] = (int)(g & 1u);
            sVote[0] = 1;                          // re-arm vote box
        }
        bcount++;
        __syncthreads();
        return sVote[1];
    };

    // one Sinkhorn half-step: gout[row] = INV_N / (S_row . gin)
    auto halfstep = [&](const __half* S, const float* gin, float* gout, bool constU, bool vote){
        float4 ua[8];
        if(!constU){
            const float4* g4 = (const float4*)(gin + lane*32);
#pragma unroll
            for(int j=0;j<8;++j) ua[j]=g4[j];
        }
        const int rpw = (m==1)?1:2;
        for(int rr=0; rr<rpw; ++rr){
            int rl = w*rpw + rr;
            const float4* k4 = (const float4*)(S + (size_t)rl*2048);
            float s=0.f;
#pragma unroll
            for(int i=0;i<4;++i){
                float4 kb = k4[i*64+lane];
                const __half2* h=(const __half2*)&kb;
                float2 f0=__half22float2(h[0]),f1=__half22float2(h[1]),
                       f2=__half22float2(h[2]),f3=__half22float2(h[3]);
                if(constU) s += f0.x+f0.y+f1.x+f1.y+f2.x+f2.y+f3.x+f3.y;
                else s += f0.x*ua[2*i].x+f0.y*ua[2*i].y+f1.x*ua[2*i].z+f1.y*ua[2*i].w
                        + f2.x*ua[2*i+1].x+f2.y*ua[2*i+1].y+f3.x*ua[2*i+1].z+f3.y*ua[2*i+1].w;
            }
            s = waveReduceSum(s);
            if(constU) s *= INV_N;
            float nv = INV_N/s;
            if(lane==0){
                if(vote){
                    float ov = gout[row0+rl];
                    if(!(fabsf(nv-ov) <= TOL*nv)) sVote[0]=0;
                }
                gout[row0+rl] = nv;
            }
        }
    };

    for(int t=0; t<PROX; ++t){
        // log v_j for own columns (prev-stage converged v'); stable through phases
        float lv0=0.f, lv1=0.f, lvt=0.f;
        if(t){
            lv0 = __logf(vm[tid]);
            lv1 = __logf(vm[tid+1024]);
            if(m==1) lvt = __logf(vm[row0+(tid&15)]);
        }
        // ---- phase A: global max of M; log P derived from u, v, K_prev(LDS) ----
        float mx = -1e30f;
        for(int r=0;r<nrows;++r){
            size_t base = (size_t)(row0+r)*N;
            float c0 = Cm[base+tid], c1 = Cm[base+tid+1024];
            float m0, m1;
            if(t==0){ m0 = c0 - REG*lp0; m1 = c1 - REG*lp0; }
            else {
                float lu = __logf(um[row0+r]);
                float k0 = __half2float(Kl[r*2048+swz(tid)]);
                float k1 = __half2float(Kl[r*2048+swz(tid+1024)]);
                m0 = c0 - REG*(lu + lv0 + __logf(k0));
                m1 = c1 - REG*(lu + lv1 + __logf(k1));
            }
            mx = fmaxf(mx, fmaxf(m0, m1));
        }
        mx = waveReduceMax(mx);
        if(lane==0) sRed[w]=mx;
        __syncthreads();
        if(tid==0){
            float bm=sRed[0];
#pragma unroll
            for(int i=1;i<16;++i) bm=fmaxf(bm,sRed[i]);
            atomicMax((unsigned int*)&maxsl[m*SYS+t], __float_as_uint(bm)); // all M > 0
        }
        MATBARV(0);
        float invmx = 1.0f / maxsl[m*SYS+t];
        // ---- phase B: K_new = KSCALE*exp(-10*Mhat), in-place elementwise over K_prev ----
        for(int r=0;r<nrows;++r){
            size_t base=(size_t)(row0+r)*N;
            float lu = t ? __logf(um[row0+r]) : 0.f;
            {
                float c0 = Cm[base+tid];
                float m0 = (t==0) ? (c0 - REG*lp0)
                    : (c0 - REG*(lu + lv0 + __logf(__half2float(Kl[r*2048+swz(tid)]))));
                Kl[r*2048+swz(tid)] = __float2half(__expf(m0*invmx*-10.0f)*KSCALE);
                float c1 = Cm[base+tid+1024];
                float m1 = (t==0) ? (c1 - REG*lp0)
                    : (c1 - REG*(lu + lv1 + __logf(__half2float(Kl[r*2048+swz(tid+1024)]))));
                Kl[r*2048+swz(tid+1024)] = __float2half(__expf(m1*invmx*-10.0f)*KSCALE);
            }
        }
        if(m==1){
            for(int pass=0;pass<32;++pass){
                int i = pass*64 + (tid>>4); int jj = tid&15;
                float cc = Cm[(size_t)i*N + row0 + jj];
                float Mv;
                if(t==0) Mv = cc - REG*lp0;
                else {
                    float lu = __logf(um[i]);
                    float kp = __half2float(KTl[jj*2048+swz(i)]);
                    Mv = cc - REG*(lu + lvt + __logf(kp));
                }
                KTl[jj*2048+swz(i)] = __float2half(__expf(Mv*invmx*-10.0f)*KSCALE);
            }
        }
        __syncthreads();
        // ---- Sinkhorn loop (warm-started u; fused-vote latch) ----
        for(int it=0; it<SINK; ++it){
            halfstep((m==1)?KTl:Kl, um, vm, (t==0 && it==0), false);  // v = q/(K^T u)
            MATBARV(0);
            halfstep(Kl, vm, um, false, true);                        // u = p/(K v), vote
            int flag = MATBARV(it>=3);
            if(flag) break;                                           // uniform per matrix
        }
        halfstep((m==1)?KTl:Kl, um, vm, false, false);                // final v
        MATBARV(0);
        // ---- P build only where needed (t=3 -> Pb = T_pre, t=4 -> Pa = T) ----
        if(t>=3){
            float* Pom = ((t&1) ? Pb : Pa) + (size_t)m*NM;
            for(int r=0;r<nrows;++r){
                size_t base=(size_t)(row0+r)*N;
                float uu = um[row0+r];
                float k0 = __half2float(Kl[r*2048+swz(tid)]);
                float k1 = __half2float(Kl[r*2048+swz(tid+1024)]);
                Pom[base+tid]      = uu*k0*vm[tid];
                Pom[base+tid+1024] = uu*k1*vm[tid+1024];
            }
        }
        // next stage's phase-A barrier protects um/vm reads (pbuild included)
    }
}

// ---------------- column sums of normalized M_final (from C and P4) ----------------
__global__ __launch_bounds__(256) void colsumM_k(const float* __restrict__ Cb,
                                                 const float* __restrict__ Pb,
                                                 const float* __restrict__ maxsl, int slot,
                                                 float* __restrict__ colM){
    int mat = blockIdx.y;
    const float4* C4 = (const float4*)(Cb + (size_t)mat*NM);
    const float4* P4 = (const float4*)(Pb + (size_t)mat*NM);
    float invmx = 1.0f / maxsl[mat*SYS + slot];
    int r0 = blockIdx.x*32;
    float4 a0 = {0,0,0,0}, a1 = {0,0,0,0};
    for(int r=0;r<32;++r){
        int base = (r0 + r)*512;
        {
            float4 c = C4[base + threadIdx.x]; float4 p = P4[base + threadIdx.x];
            a0.x += (c.x - REG*logf(p.x+EPSF))*invmx;
            a0.y += (c.y - REG*logf(p.y+EPSF))*invmx;
            a0.z += (c.z - REG*logf(p.z+EPSF))*invmx;
            a0.w += (c.w - REG*logf(p.w+EPSF))*invmx;
        }
        {
            float4 c = C4[base + 256 + threadIdx.x]; float4 p = P4[base + 256 + threadIdx.x];
            a1.x += (c.x - REG*logf(p.x+EPSF))*invmx;
            a1.y += (c.y - REG*logf(p.y+EPSF))*invmx;
            a1.z += (c.z - REG*logf(p.z+EPSF))*invmx;
            a1.w += (c.w - REG*logf(p.w+EPSF))*invmx;
        }
    }
    float* cm = colM + mat*N;
    atomicAdd(cm + 4*threadIdx.x + 0, a0.x);
    atomicAdd(cm + 4*threadIdx.x + 1, a0.y);
    atomicAdd(cm + 4*threadIdx.x + 2, a0.z);
    atomicAdd(cm + 4*threadIdx.x + 3, a0.w);
    atomicAdd(cm + 1024 + 4*threadIdx.x + 0, a1.x);
    atomicAdd(cm + 1024 + 4*threadIdx.x + 1, a1.y);
    atomicAdd(cm + 1024 + 4*threadIdx.x + 2, a1.z);
    atomicAdd(cm + 1024 + 4*threadIdx.x + 3, a1.w);
}

// ---------------- column sums of T (=P5) and log(T+eps) ----------------
__global__ __launch_bounds__(256) void colsumTL_k(const float* __restrict__ Pb,
                                                  float* __restrict__ colT,
                                                  float* __restrict__ colL){
    int mat = blockIdx.y;
    const float4* P4 = (const float4*)(Pb + (size_t)mat*NM);
    int r0 = blockIdx.x*32;
    float4 t0 = {0,0,0,0}, t1 = {0,0,0,0};
    float4 l0 = {0,0,0,0}, l1 = {0,0,0,0};
    for(int r=0;r<32;++r){
        int base = (r0 + r)*512;
        {
            float4 p = P4[base + threadIdx.x];
            t0.x += p.x; t0.y += p.y; t0.z += p.z; t0.w += p.w;
            l0.x += logf(p.x+EPSF); l0.y += logf(p.y+EPSF);
            l0.z += logf(p.z+EPSF); l0.w += logf(p.w+EPSF);
        }
        {
            float4 p = P4[base + 256 + threadIdx.x];
            t1.x += p.x; t1.y += p.y; t1.z += p.z; t1.w += p.w;
            l1.x += logf(p.x+EPSF); l1.y += logf(p.y+EPSF);
            l1.z += logf(p.z+EPSF); l1.w += logf(p.w+EPSF);
        }
    }
    float* ct = colT + mat*N;
    float* cl = colL + mat*N;
    atomicAdd(ct + 4*threadIdx.x + 0, t0.x);
    atomicAdd(ct + 4*threadIdx.x + 1, t0.y);
    atomicAdd(ct + 4*threadIdx.x + 2, t0.z);
    atomicAdd(ct + 4*threadIdx.x + 3, t0.w);
    atomicAdd(ct + 1024 + 4*threadIdx.x + 0, t1.x);
    atomicAdd(ct + 1024 + 4*threadIdx.x + 1, t1.y);
    atomicAdd(ct + 1024 + 4*threadIdx.x + 2, t1.z);
    atomicAdd(ct + 1024 + 4*threadIdx.x + 3, t1.w);
    atomicAdd(cl + 4*threadIdx.x + 0, l0.x);
    atomicAdd(cl + 4*threadIdx.x + 1, l0.y);
    atomicAdd(cl + 4*threadIdx.x + 2, l0.z);
    atomicAdd(cl + 4*threadIdx.x + 3, l0.w);
    atomicAdd(cl + 1024 + 4*threadIdx.x + 0, l1.x);
    atomicAdd(cl + 1024 + 4*threadIdx.x + 1, l1.y);
    atomicAdd(cl + 1024 + 4*threadIdx.x + 2, l1.z);
    atomicAdd(cl + 1024 + 4*threadIdx.x + 3, l1.w);
}

// ---------------- final combine ----------------
__global__ __launch_bounds__(256) void final_k(const float* __restrict__ colM,
                                               const float* __restrict__ colT,
                                               const float* __restrict__ colL,
                                               float* __restrict__ out){
    __shared__ float red[8];
    __shared__ float divs[3];
    for(int mat=0; mat<3; ++mat){
        float s1=0.f, s2=0.f;
        for(int j=threadIdx.x; j<N; j+=256){
            float t = colT[mat*N+j];
            s1 += t * colM[mat*N+j];
            s2 += t * (colL[mat*N+j] - (float)N);
        }
        s1 = waveReduceSum(s1); s2 = waveReduceSum(s2);
        int w = threadIdx.x>>6, lane = threadIdx.x&63;
        if(lane==0){ red[w] = s1; red[4+w] = s2; }
        __syncthreads();
        if(threadIdx.x==0){
            float a = red[0]+red[1]+red[2]+red[3];
            float b = red[4]+red[5]+red[6]+red[7];
            divs[mat] = (a + REG*b) * (1.0f/((float)N*(float)N));
        }
        __syncthreads();
    }
    if(threadIdx.x==0) out[0] = divs[1] - 0.5f*(divs[0] + divs[2]);
}

extern "C" void kernel_launch(void* const* d_in, const int* in_sizes, int n_in,
                              void* d_out, int out_size, void* d_ws, size_t ws_size,
                              hipStream_t stream){
    const float* x = (const float*)d_in[0];
    const float* y = (const float*)d_in[1];
    float* ws = (float*)d_ws;
    // layout: C[3NM] Pa[3NM] Pb[3NM] | ug[3N] vg[3N] nx[N] ny[N] | zeroed tail
    float* C    = ws;
    float* Pa   = C  + (size_t)3*NM;
    float* Pb   = Pa + (size_t)3*NM;
    float* ug   = Pb + (size_t)3*NM;
    float* vg   = ug + 3*N;
    float* nx   = vg + 3*N;
    float* ny   = nx + N;
    float* zb   = ny + N;
    float* maxsl= zb;                   // 3*SYS floats (padded per matrix)
    float* colM = zb + 3*SYS;           // 3N
    float* colT = colM + 3*N;           // 3N
    float* colL = colT + 3*N;           // 3N
    int*   sync_= (int*)(colL + 3*N);   // 3*SLOTS_PER_MAT*SYS ints, padded slots
    size_t zbytes = ((size_t)3*SYS + 9*N)*sizeof(float)
                  + (size_t)3*SLOTS_PER_MAT*SYS*sizeof(int);
    hipMemsetAsync(zb, 0, zbytes, stream);

    norms_k <<<dim3(512,2), 256, 0, stream>>>(x, y, nx, ny);
    sqdist_k<<<dim3(1024,3),256, 0, stream>>>(x, y, nx, ny, C);

    hipFuncSetAttribute((const void*)coop_k,
                        hipFuncAttributeMaxDynamicSharedMemorySize, SMEM_BYTES);
    void* args[] = {(void*)&C, (void*)&Pa, (void*)&Pb, (void*)&ug, (void*)&vg,
                    (void*)&maxsl, (void*)&sync_};
    hipLaunchCooperativeKernel((void*)coop_k, dim3(256), dim3(1024),
                               args, SMEM_BYTES, stream);

    // P4 (T_pre) in Pb (stage 3), P5 (T) in Pa (stage 4)
    colsumM_k <<<dim3(64,3), 256, 0, stream>>>(C, Pb, maxsl, 4, colM);
    colsumTL_k<<<dim3(64,3), 256, 0, stream>>>(Pa, colT, colL);
    final_k   <<<1, 256, 0, stream>>>(colM, colT, colL, (float*)d_out);
}